// Round 1
// baseline (75.122 us; speedup 1.0000x reference)
//
#include <hip/hip_runtime.h>

typedef __bf16 bf16_t;
typedef __bf16 bf16x2 __attribute__((ext_vector_type(2)));
typedef __bf16 bf16x4 __attribute__((ext_vector_type(4)));
typedef __bf16 bf16x8 __attribute__((ext_vector_type(8)));
typedef float  f32x4  __attribute__((ext_vector_type(4)));

#define MFMA16(a, b, c) __builtin_amdgcn_mfma_f32_16x16x32_bf16((a), (b), (c), 0, 0, 0)

// ---------------- LDS layout (bytes) ----------------
// region X [0, 17408):    x tile [64][136] bf16  --(after b2)--> mask [49][52] f32
//                         --(after b5)--> att [64][136] bf16
// per head h in 0..3: base = 17408 + h*14848:
//   q  [64][40] bf16 (5120 B)   } overlaid by p [64][72] bf16 (9216 B) after b4
//   k  [64][40] bf16 (5120 B)   }
//   vT [32][72] bf16 (4608 B)
// total = 17408 + 4*14848 = 76800
#define SMEM_BYTES 76800

// Fragment conventions for v_mfma_f32_16x16x32_bf16, D = A*B:
//  A (MxK): lane holds A[lane&15][8*(lane>>4)+i], i=0..7   (row-major MxK read)
//  B (KxN): lane holds B[8*(lane>>4)+i][lane&15]           (row-major NxK read, i.e. B^T)
//  D (MxN): lane reg r holds D[4*(lane>>4)+r][lane&15]     (verified m89/m91)

__global__ void wconv_kernel(const float* __restrict__ qw, const float* __restrict__ pw,
                             bf16_t* __restrict__ o) {
    int i = (blockIdx.x * 256 + threadIdx.x) * 4;   // 64 blocks * 256 thr * 4 = 65536
    const float* src = (i < 49152) ? (qw + i) : (pw + (i - 49152));
    float4 f = *(const float4*)src;
    bf16x4 h;
    h[0] = (bf16_t)f.x; h[1] = (bf16_t)f.y; h[2] = (bf16_t)f.z; h[3] = (bf16_t)f.w;
    *(bf16x4*)(o + i) = h;
}

__device__ __forceinline__ bf16x8 ldw(const float* __restrict__ wf,
                                      const bf16_t* __restrict__ wb,
                                      int use_b, int idx) {
    if (use_b) {
        return *(const bf16x8*)(wb + idx);
    } else {
        float4 f0 = *(const float4*)(wf + idx);
        float4 f1 = *(const float4*)(wf + idx + 4);
        bf16x8 r;
        r[0] = (bf16_t)f0.x; r[1] = (bf16_t)f0.y; r[2] = (bf16_t)f0.z; r[3] = (bf16_t)f0.w;
        r[4] = (bf16_t)f1.x; r[5] = (bf16_t)f1.y; r[6] = (bf16_t)f1.z; r[7] = (bf16_t)f1.w;
        return r;
    }
}

__global__ __launch_bounds__(512, 4) void winattn_kernel(
    const float* __restrict__ xg, const float* __restrict__ maskg,
    const float* __restrict__ qwg, const float* __restrict__ qbg,
    const float* __restrict__ pwg, const float* __restrict__ pbg,
    const bf16_t* __restrict__ wqb, const bf16_t* __restrict__ wpb,
    const int use_wbf, const int nW, float* __restrict__ outg)
{
    extern __shared__ char smem[];
    bf16_t* xatt  = (bf16_t*)smem;   // [64][136] bf16 (x, later att)
    float*  maskl = (float*)smem;    // [49][52] f32 overlay (between b2 and b5)

    const int b    = blockIdx.x;
    const int tid  = threadIdx.x;
    const int w    = tid >> 6;       // wave 0..7
    const int lane = tid & 63;
    const int g    = lane >> 4;      // lane group 0..3
    const int c0   = lane & 15;

    // ---- phase 0: stage x (49x128 f32 -> bf16 LDS), zero rows 49..63 ----
    {
        const float4* xb = (const float4*)(xg + (long)b * 6272);
        #pragma unroll 4
        for (int i = tid; i < 1568; i += 512) {
            float4 f = xb[i];
            int row = i >> 5;
            int col = (i & 31) << 2;
            bf16x4 h;
            h[0] = (bf16_t)f.x; h[1] = (bf16_t)f.y; h[2] = (bf16_t)f.z; h[3] = (bf16_t)f.w;
            *(bf16x4*)(xatt + row * 136 + col) = h;
        }
        unsigned int* z = (unsigned int*)(xatt + 49 * 136);
        for (int i = tid; i < 1020; i += 512) z[i] = 0u;
    }
    __syncthreads();   // b1

    // ---- phase 1: QKV GEMM: qkv[token][o] = x @ qkv_w^T + b ----
    {
        f32x4 acc[3][4];
        #pragma unroll
        for (int nt = 0; nt < 3; ++nt)
            #pragma unroll
            for (int mt = 0; mt < 4; ++mt) acc[nt][mt] = {0.f, 0.f, 0.f, 0.f};

        #pragma unroll
        for (int ks = 0; ks < 4; ++ks) {
            bf16x8 a[4];
            #pragma unroll
            for (int mt = 0; mt < 4; ++mt)
                a[mt] = *(const bf16x8*)(xatt + (mt * 16 + c0) * 136 + ks * 32 + g * 8);
            #pragma unroll
            for (int nt = 0; nt < 3; ++nt) {
                int o   = (w * 3 + nt) * 16 + c0;
                bf16x8 bb = ldw(qwg, wqb, use_wbf, o * 128 + ks * 32 + g * 8);
                #pragma unroll
                for (int mt = 0; mt < 4; ++mt)
                    acc[nt][mt] = MFMA16(a[mt], bb, acc[nt][mt]);
            }
        }
        // scatter D into q / k / vT per head
        #pragma unroll
        for (int nt = 0; nt < 3; ++nt) {
            int og   = (w * 3 + nt) * 16;
            float bias = qbg[og + c0];
            int part = og >> 7;            // 0=q 1=k 2=v
            int rem  = og & 127;
            int hh   = rem >> 5;           // head
            int dh   = (rem & 31) + c0;    // 0..31
            bf16_t* hb = (bf16_t*)(smem + 17408 + hh * 14848);
            #pragma unroll
            for (int mt = 0; mt < 4; ++mt) {
                #pragma unroll
                for (int r = 0; r < 4; ++r) {
                    int row   = mt * 16 + g * 4 + r;   // token
                    float val = acc[nt][mt][r] + bias;
                    if (part == 0)      hb[row * 40 + dh]        = (bf16_t)val;  // q [tok][dh]
                    else if (part == 1) hb[2560 + row * 40 + dh] = (bf16_t)val;  // k [tok][dh]
                    else                hb[5120 + dh * 72 + row] = (bf16_t)val;  // vT [dh][tok]
                }
            }
        }
    }
    __syncthreads();   // b2: q/k/vT visible; x dead

    // ---- phase 2: stage mask[b % nW] into x region ----
    {
        const float* mb = maskg + (long)(b % nW) * 2401;
        for (int i = tid; i < 2401; i += 512)
            maskl[(i / 49) * 52 + (i % 49)] = mb[i];
    }
    __syncthreads();   // b3

    // ---- phase 3: preload QK^T fragments (q/k die after this) ----
    const int h   = w >> 1;    // head
    const int qh2 = w & 1;     // which 32 q-rows
    bf16_t* qls = (bf16_t*)(smem + 17408 + h * 14848);
    bf16_t* kls = qls + 2560;
    bf16_t* vls = qls + 5120;
    bf16_t* pls = qls;         // p overlays q+k
    bf16x8 ka[4], qb2[2];
    #pragma unroll
    for (int mt = 0; mt < 4; ++mt)
        ka[mt] = *(const bf16x8*)(kls + (mt * 16 + c0) * 40 + g * 8);
    #pragma unroll
    for (int nt = 0; nt < 2; ++nt)
        qb2[nt] = *(const bf16x8*)(qls + ((qh2 * 2 + nt) * 16 + c0) * 40 + g * 8);
    __syncthreads();   // b4: all q/k reads done before p writes

    // ---- phase 4: S^T = K·Q^T (swapped), softmax over kv, P -> LDS ----
    {
        f32x4 s[2][4];
        #pragma unroll
        for (int nt = 0; nt < 2; ++nt)
            #pragma unroll
            for (int mt = 0; mt < 4; ++mt) s[nt][mt] = {0.f, 0.f, 0.f, 0.f};
        #pragma unroll
        for (int nt = 0; nt < 2; ++nt)
            #pragma unroll
            for (int mt = 0; mt < 4; ++mt)
                s[nt][mt] = MFMA16(ka[mt], qb2[nt], s[nt][mt]);   // D[kv][q]

        const float scale = 0.17677669529663687f;   // 32^-0.5
        #pragma unroll
        for (int nt = 0; nt < 2; ++nt) {
            int q  = (qh2 * 2 + nt) * 16 + c0;
            int qm = q < 49 ? q : 48;                // rows >=49: finite garbage, never stored
            float lg[16];
            float m = -1e30f;
            #pragma unroll
            for (int mt = 0; mt < 4; ++mt) {
                #pragma unroll
                for (int r = 0; r < 4; ++r) {
                    int kv  = mt * 16 + g * 4 + r;
                    float v = (kv < 49) ? (s[nt][mt][r] * scale + maskl[qm * 52 + kv])
                                        : -1e30f;
                    lg[mt * 4 + r] = v;
                    m = fmaxf(m, v);
                }
            }
            // kv values for a fixed q live in lanes c0, c0+16, c0+32, c0+48
            m = fmaxf(m, __shfl_xor(m, 16));
            m = fmaxf(m, __shfl_xor(m, 32));
            float sum = 0.f;
            #pragma unroll
            for (int i = 0; i < 16; ++i) { float e = __expf(lg[i] - m); lg[i] = e; sum += e; }
            sum += __shfl_xor(sum, 16);
            sum += __shfl_xor(sum, 32);
            float inv = 1.f / sum;
            #pragma unroll
            for (int mt = 0; mt < 4; ++mt) {
                #pragma unroll
                for (int j = 0; j < 2; ++j) {
                    bf16x2 t;
                    t[0] = (bf16_t)(lg[mt * 4 + 2 * j    ] * inv);
                    t[1] = (bf16_t)(lg[mt * 4 + 2 * j + 1] * inv);
                    *(bf16x2*)(pls + q * 72 + mt * 16 + g * 4 + 2 * j) = t;  // p [q][kv]
                }
            }
        }
    }
    __syncthreads();   // b5: mask reads done before att overwrites region X

    // ---- phase 5: out^T = V^T · P^T, write att[token][c] ----
    {
        f32x4 oo[2][2];
        #pragma unroll
        for (int mt = 0; mt < 2; ++mt)
            #pragma unroll
            for (int nt = 0; nt < 2; ++nt) oo[mt][nt] = {0.f, 0.f, 0.f, 0.f};
        #pragma unroll
        for (int ks = 0; ks < 2; ++ks) {
            bf16x8 va[2], pb2[2];
            #pragma unroll
            for (int mt = 0; mt < 2; ++mt)
                va[mt] = *(const bf16x8*)(vls + (mt * 16 + c0) * 72 + ks * 32 + g * 8);
            #pragma unroll
            for (int nt = 0; nt < 2; ++nt)
                pb2[nt] = *(const bf16x8*)(pls + ((qh2 * 2 + nt) * 16 + c0) * 72 + ks * 32 + g * 8);
            #pragma unroll
            for (int mt = 0; mt < 2; ++mt)
                #pragma unroll
                for (int nt = 0; nt < 2; ++nt)
                    oo[mt][nt] = MFMA16(va[mt], pb2[nt], oo[mt][nt]);  // D[dh][q]
        }
        #pragma unroll
        for (int nt = 0; nt < 2; ++nt) {
            int q = (qh2 * 2 + nt) * 16 + c0;
            #pragma unroll
            for (int mt = 0; mt < 2; ++mt) {
                #pragma unroll
                for (int j = 0; j < 2; ++j) {
                    bf16x2 t;
                    t[0] = (bf16_t)oo[mt][nt][2 * j];
                    t[1] = (bf16_t)oo[mt][nt][2 * j + 1];
                    *(bf16x2*)(xatt + q * 136 + h * 32 + mt * 16 + g * 4 + 2 * j) = t;
                }
            }
        }
    }
    __syncthreads();   // b6

    // ---- phase 6: proj GEMM + bias + store ----
    {
        f32x4 acc[4];
        #pragma unroll
        for (int mt = 0; mt < 4; ++mt) acc[mt] = {0.f, 0.f, 0.f, 0.f};
        int col = w * 16 + c0;
        #pragma unroll
        for (int ks = 0; ks < 4; ++ks) {
            bf16x8 a[4];
            #pragma unroll
            for (int mt = 0; mt < 4; ++mt)
                a[mt] = *(const bf16x8*)(xatt + (mt * 16 + c0) * 136 + ks * 32 + g * 8);
            bf16x8 bb = ldw(pwg, wpb, use_wbf, col * 128 + ks * 32 + g * 8);
            #pragma unroll
            for (int mt = 0; mt < 4; ++mt)
                acc[mt] = MFMA16(a[mt], bb, acc[mt]);
        }
        float pb = pbg[col];
        float* ob = outg + (long)b * 6272;
        #pragma unroll
        for (int mt = 0; mt < 4; ++mt) {
            #pragma unroll
            for (int r = 0; r < 4; ++r) {
                int q = mt * 16 + g * 4 + r;
                if (q < 49) ob[q * 128 + col] = acc[mt][r] + pb;
            }
        }
    }
}

extern "C" void kernel_launch(void* const* d_in, const int* in_sizes, int n_in,
                              void* d_out, int out_size, void* d_ws, size_t ws_size,
                              hipStream_t stream) {
    const float* xg  = (const float*)d_in[0];
    const float* mg  = (const float*)d_in[1];
    const float* qwg = (const float*)d_in[2];
    const float* qbg = (const float*)d_in[3];
    const float* pwg = (const float*)d_in[4];
    const float* pbg = (const float*)d_in[5];
    float* outg = (float*)d_out;

    const int B  = in_sizes[0] / (49 * 128);   // 2048
    const int nW = in_sizes[1] / (49 * 49);    // 64

    // Pre-convert weights to bf16 into workspace if it is large enough.
    int use_wbf = (d_ws != nullptr && ws_size >= 131072) ? 1 : 0;
    bf16_t* wqb = (bf16_t*)d_ws;
    bf16_t* wpb = use_wbf ? (wqb + 49152) : nullptr;
    if (use_wbf)
        wconv_kernel<<<64, 256, 0, stream>>>(qwg, pwg, wqb);

    // 76.8 KB dynamic LDS needs the opt-in (host-side, graph-capture safe)
    (void)hipFuncSetAttribute((const void*)winattn_kernel,
                              hipFuncAttributeMaxDynamicSharedMemorySize, SMEM_BYTES);

    winattn_kernel<<<B, 512, SMEM_BYTES, stream>>>(
        xg, mg, qwg, qbg, pwg, pbg, wqb, use_wbf ? wpb : wqb, use_wbf, nW, outg);
}